// Round 5
// baseline (1252.837 us; speedup 1.0000x reference)
//
#include <hip/hip_runtime.h>
#include <hip/hip_bf16.h>
#include <cstdint>

#define B_ 2
#define S_ 2048
#define D_ 1024
#define H_ 16
#define DK_ 64
#define QK_ELEMS ((size_t)4194304)   // B*H*S*DK
#define NROWS 65536                  // B*H*S
#define TAU 8e-5f

typedef __attribute__((ext_vector_type(8))) short bf16x8;
typedef __attribute__((ext_vector_type(4))) float f32x4;
typedef __attribute__((ext_vector_type(16))) float f32x16;
typedef __attribute__((ext_vector_type(4))) unsigned short us4;

__device__ __forceinline__ unsigned short f2bf(float f){
  unsigned int u = __float_as_uint(f);
  unsigned int r = u + 0x7fffu + ((u >> 16) & 1u);
  return (unsigned short)(r >> 16);
}
__device__ __forceinline__ float bf2f(unsigned short h){
  return __uint_as_float(((unsigned int)h) << 16);
}

__device__ __forceinline__ void gload16(const void* g, void* l){
  __builtin_amdgcn_global_load_lds(
    (__attribute__((address_space(1))) void*)(void*)(g),
    (__attribute__((address_space(3))) void*)(l), 16, 0, 0);
}

__device__ __forceinline__ f32x4 mfma16(bf16x8 a, bf16x8 b, f32x4 c){
  return __builtin_amdgcn_mfma_f32_16x16x32_bf16(a, b, c, 0, 0, 0);
}
__device__ __forceinline__ f32x16 mfma32(bf16x8 a, bf16x8 b, f32x16 c){
  return __builtin_amdgcn_mfma_f32_32x32x16_bf16(a, b, c, 0, 0, 0);
}

// ---------------- conversion: fp32 -> bf16 (hi/lo splits where needed) ----------------
__global__ __launch_bounds__(256) void convert_all(
  const float* __restrict__ x,  const float* __restrict__ Wq, const float* __restrict__ Wk,
  const float* __restrict__ Wv, const float* __restrict__ Wo, const float* __restrict__ W1,
  const float* __restrict__ W2,
  unsigned short* __restrict__ xh, unsigned short* __restrict__ xl,
  unsigned short* __restrict__ Wqkh, unsigned short* __restrict__ Wqkl,
  unsigned short* __restrict__ Wvb, unsigned short* __restrict__ Wob,
  unsigned short* __restrict__ W1b, unsigned short* __restrict__ W2b)
{
  const long total = 16777216 / 4;
  for (long i = (long)blockIdx.x * blockDim.x + threadIdx.x; i < total;
       i += (long)gridDim.x * blockDim.x) {
    long e = i * 4;
    const float* src; unsigned short* dh; unsigned short* dl = nullptr; long o;
    if      (e < 4194304)  { src = x;  dh = xh;            dl = xl;            o = e; }
    else if (e < 5242880)  { src = Wq; dh = Wqkh;          dl = Wqkl;          o = e - 4194304; }
    else if (e < 6291456)  { src = Wk; dh = Wqkh + 1048576; dl = Wqkl + 1048576; o = e - 5242880; }
    else if (e < 7340032)  { src = Wv; dh = Wvb;           o = e - 6291456; }
    else if (e < 8388608)  { src = Wo; dh = Wob;           o = e - 7340032; }
    else if (e < 12582912) { src = W1; dh = W1b;           o = e - 8388608; }
    else                   { src = W2; dh = W2b;           o = e - 12582912; }
    float4 v = *(const float4*)(src + o);
    us4 h;
    h.x = f2bf(v.x); h.y = f2bf(v.y); h.z = f2bf(v.z); h.w = f2bf(v.w);
    *(us4*)(dh + o) = h;
    if (dl) {
      us4 L;
      L.x = f2bf(v.x - bf2f(h.x));
      L.y = f2bf(v.y - bf2f(h.y));
      L.z = f2bf(v.z - bf2f(h.z));
      L.w = f2bf(v.w - bf2f(h.w));
      *(us4*)(dl + o) = L;
    }
  }
}

// ---------------- generic B^T GEMM: C[m][n] = sum_k A[m][k]*B[n][k] ----------------
#define EPI_QK   0
#define EPI_V    1
#define EPI_WO   2
#define EPI_GELU 3
#define EPI_OUT  4

template<int NT, int EPI>
__global__ __launch_bounds__(256) void gemm_bt(
  const unsigned short* __restrict__ A,  const unsigned short* __restrict__ Alo,
  const unsigned short* __restrict__ Bm, const unsigned short* __restrict__ Blo,
  int M, int N, int K,
  const float* __restrict__ bias0, const float* __restrict__ bias1,
  const float* __restrict__ gsc,
  void* __restrict__ out0, void* __restrict__ out1)
{
  constexpr int NTILES = (NT > 1) ? 4 : 2;
  __shared__ char lds[NTILES * 8192];
  char* Ahl = lds;
  char* Bhl = lds + 8192;
  char* All = lds + 16384;
  char* Bll = lds + 24576;
  const int tid = threadIdx.x;
  const int wid = tid >> 6, lane = tid & 63;
  const int mtile = blockIdx.y, ntile = blockIdx.x;
  const int wm = wid >> 1, wn = wid & 1;

  f32x4 acc[4][4];
  #pragma unroll
  for (int i = 0; i < 4; i++)
    #pragma unroll
    for (int j = 0; j < 4; j++)
      #pragma unroll
      for (int r = 0; r < 4; r++) acc[i][j][r] = 0.f;

  const unsigned short* Abase  = A  + (size_t)(mtile * 128) * K;
  const unsigned short* Bbase  = Bm + (size_t)(ntile * 128) * K;
  const unsigned short* Albase = (NT > 1) ? Alo + (size_t)(mtile * 128) * K : nullptr;
  const unsigned short* Blbase = (NT > 1) ? Blo + (size_t)(ntile * 128) * K : nullptr;

  auto stage = [&](char* ldst, const unsigned short* gsrc, int kb){
    #pragma unroll
    for (int j = 0; j < 2; j++){
      int seg = wid + 4 * j;                 // 0..7, 1KB each
      int row = seg * 16 + (lane >> 2);      // 0..127
      int c   = (lane & 3) ^ ((row >> 1) & 3);
      gload16(gsrc + (size_t)row * K + kb + c * 8, ldst + seg * 1024);
    }
  };

  for (int kb = 0; kb < K; kb += 32){
    stage(Ahl, Abase, kb);
    stage(Bhl, Bbase, kb);
    if (NT > 1){ stage(All, Albase, kb); stage(Bll, Blbase, kb); }
    __syncthreads();

    bf16x8 af[4], bfr[4], afl[4], bfl[4];
    #pragma unroll
    for (int i = 0; i < 4; i++){
      int ra = wm * 64 + i * 16 + (lane & 15);
      int oa = ra * 64 + (((lane >> 4) ^ ((ra >> 1) & 3)) * 16);
      af[i] = *(const bf16x8*)(Ahl + oa);
      if (NT > 1) afl[i] = *(const bf16x8*)(All + oa);
      int rb = wn * 64 + i * 16 + (lane & 15);
      int ob = rb * 64 + (((lane >> 4) ^ ((rb >> 1) & 3)) * 16);
      bfr[i] = *(const bf16x8*)(Bhl + ob);
      if (NT > 1) bfl[i] = *(const bf16x8*)(Bll + ob);
    }
    #pragma unroll
    for (int i = 0; i < 4; i++)
      #pragma unroll
      for (int j = 0; j < 4; j++){
        if (NT > 1){
          acc[i][j] = mfma16(afl[i], bfl[j], acc[i][j]);
          acc[i][j] = mfma16(afl[i], bfr[j], acc[i][j]);
          acc[i][j] = mfma16(af[i],  bfl[j], acc[i][j]);
        }
        acc[i][j] = mfma16(af[i], bfr[j], acc[i][j]);
      }
    __syncthreads();
  }

  float g2x = 1.0f;
  if (EPI == EPI_WO || EPI == EPI_OUT) g2x = 2.0f * gsc[0];

  #pragma unroll
  for (int j = 0; j < 4; j++){
    int n = ntile * 128 + wn * 64 + j * 16 + (lane & 15);
    float bn;
    if (EPI == EPI_QK) bn = (n < 1024) ? bias0[n] : bias1[n - 1024];
    else               bn = bias0[n];
    #pragma unroll
    for (int i = 0; i < 4; i++){
      int mb = mtile * 128 + wm * 64 + i * 16 + ((lane >> 4) << 2);
      #pragma unroll
      for (int r = 0; r < 4; r++){
        int m = mb + r;
        float val = acc[i][j][r] + bn;
        if (EPI == EPI_QK){
          if (n < 1024) val *= 0.125f;          // fold 1/sqrt(DK) into q
          int dd = n & 63, hh = (n >> 6) & 15, isK = n >> 10;
          size_t off = ((size_t)((m >> 11) * H_ + hh) * S_ + (m & 2047)) * DK_ + dd
                       + (size_t)isK * QK_ELEMS;
          unsigned short hi = f2bf(val);
          ((unsigned short*)out0)[off] = hi;
          ((unsigned short*)out1)[off] = f2bf(val - bf2f(hi));
        } else if (EPI == EPI_V){
          int dd = n & 63, hh = n >> 6;
          size_t off = ((size_t)((m >> 11) * H_ + hh) * S_ + (m & 2047)) * DK_ + dd;
          ((float*)out0)[off] = val;
        } else if (EPI == EPI_WO){
          ((unsigned short*)out0)[(size_t)m * 1024 + n] = f2bf(val * g2x);
        } else if (EPI == EPI_GELU){
          float t = 0.5f * val * (1.0f + erff(val * 0.70710678118654752f));
          ((unsigned short*)out0)[(size_t)m * 4096 + n] = f2bf(t);
        } else {
          ((float*)out0)[(size_t)m * 1024 + n] = val * g2x;
        }
      }
    }
  }
}

// ---------------- attention: causal scores + top-12 tracking + softmax + PV ----------------
template<int NK>
__device__ __forceinline__ void topk_insert(float (&tv)[NK], int (&ti)[NK],
                                            float& minv, int& minslot, float s, int kidx){
  #pragma unroll
  for (int j = 0; j < NK; j++){
    bool sel = (j == minslot);
    tv[j] = sel ? s    : tv[j];
    ti[j] = sel ? kidx : ti[j];
  }
  minv = tv[0]; minslot = 0;
  #pragma unroll
  for (int j = 1; j < NK; j++){
    bool lt = tv[j] < minv;
    minv    = lt ? tv[j] : minv;
    minslot = lt ? j     : minslot;
  }
}

__global__ __launch_bounds__(256) void attn_topk(
  const unsigned short* __restrict__ QKh, const unsigned short* __restrict__ QKl,
  const float* __restrict__ Vf, unsigned short* __restrict__ ctxb,
  int* __restrict__ cand, unsigned int* __restrict__ flags)
{
  __shared__ char lds[16384];   // Khi 8KB + Klo 8KB (64 keys x 64 dk bf16, swizzled)
  const int tid = threadIdx.x, wid = tid >> 6, lane = tid & 63;
  const int b = blockIdx.z, h = blockIdx.y, qt = blockIdx.x;
  const int bh = b * H_ + h;
  const size_t base = (size_t)bh * S_ * DK_;
  const unsigned short* qh = QKh + base;
  const unsigned short* ql = QKl + base;
  const unsigned short* kh = QKh + QK_ELEMS + base;
  const unsigned short* kl = QKl + QK_ELEMS + base;
  const int Q0  = qt * 128;
  const int q0w = Q0 + wid * 32;
  const int qg  = q0w + (lane & 31);

  bf16x8 qfh[4], qfl[4];
  #pragma unroll
  for (int kk = 0; kk < 4; kk++){
    size_t o = (size_t)(q0w + (lane & 31)) * DK_ + kk * 16 + (lane >> 5) * 8;
    qfh[kk] = *(const bf16x8*)(qh + o);
    qfl[kk] = *(const bf16x8*)(ql + o);
  }

  float tv[12]; int ti[12];
  #pragma unroll
  for (int j = 0; j < 12; j++){ tv[j] = -1e30f; ti[j] = -1; }
  float minv = -1e30f; int minslot = 0;

  const int nblocks = (Q0 + 128) >> 6;
  for (int blk = 0; blk < nblocks; ++blk){
    const int kb = blk * 64;
    #pragma unroll
    for (int j = 0; j < 4; j++){
      int segall = wid * 4 + j;          // 0..15
      int tI  = segall >> 3;             // 0: Khi, 1: Klo
      int seg = segall & 7;
      int row = seg * 8 + (lane >> 3);
      int c   = (lane & 7) ^ (row & 7);
      const unsigned short* src = (tI ? kl : kh) + (size_t)(kb + row) * DK_ + c * 8;
      gload16(src, lds + tI * 8192 + seg * 1024);
    }
    __syncthreads();

    if (kb <= q0w + 31){
      #pragma unroll
      for (int sub = 0; sub < 2; ++sub){
        f32x16 acc;
        #pragma unroll
        for (int r = 0; r < 16; r++) acc[r] = 0.f;
        const int key_l = sub * 32 + (lane & 31);
        #pragma unroll
        for (int kk = 0; kk < 4; kk++){
          int cl  = kk * 2 + (lane >> 5);
          int off = key_l * 128 + ((cl ^ (key_l & 7)) * 16);
          bf16x8 ah = *(const bf16x8*)(lds + off);
          bf16x8 al = *(const bf16x8*)(lds + 8192 + off);
          acc = mfma32(al, qfl[kk], acc);
          acc = mfma32(al, qfh[kk], acc);
          acc = mfma32(ah, qfl[kk], acc);
          acc = mfma32(ah, qfh[kk], acc);
        }
        const int krow0 = kb + sub * 32 + ((lane >> 5) << 2);
        #pragma unroll
        for (int r = 0; r < 16; r++){
          float s = acc[r];
          int kidx = krow0 + (r & 3) + ((r >> 2) << 3);
          if ((kidx <= qg) && (s > minv))
            topk_insert(tv, ti, minv, minslot, s, kidx);
        }
      }
    }
    __syncthreads();
  }

  // merge the two key-halves (lane and lane^32 hold same q-row)
  {
    float sv[12]; int si[12];
    #pragma unroll
    for (int j = 0; j < 12; j++){ sv[j] = tv[j]; si[j] = ti[j]; }
    #pragma unroll
    for (int j = 0; j < 12; j++){
      float ov = __shfl_xor(sv[j], 32);
      int   oi = __shfl_xor(si[j], 32);
      if (ov > minv) topk_insert(tv, ti, minv, minslot, ov, oi);
    }
  }

  // stable sorted top-9 pick (ties -> lowest key index first, like lax.top_k)
  float t8v[9]; int t8i[9];
  {
    float sv[12]; int si[12];
    #pragma unroll
    for (int j = 0; j < 12; j++){ sv[j] = tv[j]; si[j] = ti[j]; }
    #pragma unroll
    for (int r = 0; r < 9; r++){
      float m = sv[0];
      #pragma unroll
      for (int j = 1; j < 12; j++) m = fmaxf(m, sv[j]);
      int jidx = 0x7fffffff;
      #pragma unroll
      for (int j = 0; j < 12; j++) if (sv[j] == m) jidx = min(jidx, si[j]);
      #pragma unroll
      for (int j = 0; j < 12; j++) if (sv[j] == m && si[j] == jidx) sv[j] = -3e30f;
      t8v[r] = m; t8i[r] = jidx;
    }
  }

  // candidate dump + near-tie flag (rescue pass re-ranks flagged rows in fp64).
  // q<8 rows: <=8 valid keys, all kept regardless of ordering -> selection exact, skip.
  if (lane < 32){
    int row = bh * S_ + qg;
    #pragma unroll
    for (int c = 0; c < 12; c++) cand[row * 12 + c] = ti[c];
    flags[row] = (qg >= 8 && (t8v[7] - t8v[8] < TAU)) ? 1u : 0u;
  }

  // softmax over kept 8 (sentinels exp() to 0)
  float m = t8v[0];
  float w[8]; float Z = 0.f;
  #pragma unroll
  for (int j = 0; j < 8; j++){ w[j] = __expf(t8v[j] - m); Z += w[j]; }
  float inv = 1.0f / Z;

  float cacc[32];
  #pragma unroll
  for (int t = 0; t < 32; t++) cacc[t] = 0.f;
  const int half = lane >> 5;
  const float* vb = Vf + base + half * 32;
  #pragma unroll 2
  for (int j = 0; j < 8; j++){
    float p = w[j] * inv;
    int idx = t8i[j] < 0 ? 0 : t8i[j];
    const float4* vp = (const float4*)(vb + (size_t)idx * DK_);
    #pragma unroll
    for (int t = 0; t < 8; t++){
      float4 vv = vp[t];
      cacc[4*t+0] += p * vv.x; cacc[4*t+1] += p * vv.y;
      cacc[4*t+2] += p * vv.z; cacc[4*t+3] += p * vv.w;
    }
  }

  unsigned short* dst = ctxb + ((size_t)b * S_ + qg) * D_ + h * DK_ + half * 32;
  #pragma unroll
  for (int t = 0; t < 4; t++){
    union { unsigned short u[8]; uint4 v; } pk;
    #pragma unroll
    for (int e = 0; e < 8; e++) pk.u[e] = f2bf(cacc[8*t + e]);
    *(uint4*)(dst + 8*t) = pk.v;
  }
}

// ---------------- rescue: fp64-exact re-rank of near-tie rows ----------------
// One wave per row. All 30 float4 loads of an e-chunk are issued into explicit
// fully-unrolled register arrays BEFORE any FMA consumes them (round-4 profile
// showed VGPR=52 -> compiler serialized load->wait->use per candidate, ~13
// memory latencies per chunk). No launch_bounds: let the allocator take ~200
// VGPRs; occupancy is irrelevant (~100 active waves total).
__global__ void rescue(
  const float* __restrict__ x, const float* __restrict__ Wq, const float* __restrict__ bq,
  const float* __restrict__ Wk, const float* __restrict__ bk,
  const float* __restrict__ Vf, const int* __restrict__ cand,
  const unsigned int* __restrict__ flags, unsigned short* __restrict__ ctxb)
{
  const int row = blockIdx.x * 4 + (threadIdx.x >> 6);   // one wave per row
  if (!flags[row]) return;                               // wave-uniform early exit
  const int lane = threadIdx.x & 63;
  const int b = row >> 15, h = (row >> 11) & 15, q = row & 2047;

  int ci[12];
  const float* xc[12];
  #pragma unroll
  for (int c = 0; c < 12; c++){
    int k0 = cand[row * 12 + c];
    ci[c] = k0;
    int ki = (k0 < 0 || k0 > q) ? 0 : k0;
    xc[c] = x + ((size_t)b * S_ + ki) * D_;
  }
  const float* xr  = x  + ((size_t)b * S_ + q) * D_;
  const float* wqr = Wq + (size_t)(h * DK_ + lane) * D_;
  const float* wkr = Wk + (size_t)(h * DK_ + lane) * D_;

  double qd = 0.0, sc[12];
  #pragma unroll
  for (int c = 0; c < 12; c++) sc[c] = 0.0;

  for (int e = 0; e < D_; e += 8){
    // ---- load phase: all 30 float4s issued back-to-back ----
    float4 wq0 = *(const float4*)(wqr + e), wq1 = *(const float4*)(wqr + e + 4);
    float4 wk0 = *(const float4*)(wkr + e), wk1 = *(const float4*)(wkr + e + 4);
    float4 x0  = *(const float4*)(xr  + e), x1  = *(const float4*)(xr  + e + 4);
    float4 a0[12], a1[12];
    #pragma unroll
    for (int c = 0; c < 12; c++){
      a0[c] = *(const float4*)(xc[c] + e);
      a1[c] = *(const float4*)(xc[c] + e + 4);
    }
    // ---- compute phase ----
    qd += ((double)x0.x * wq0.x + (double)x0.y * wq0.y)
        + ((double)x0.z * wq0.z + (double)x0.w * wq0.w)
        + ((double)x1.x * wq1.x + (double)x1.y * wq1.y)
        + ((double)x1.z * wq1.z + (double)x1.w * wq1.w);
    #pragma unroll
    for (int c = 0; c < 12; c++){
      sc[c] += ((double)a0[c].x * wk0.x + (double)a0[c].y * wk0.y)
             + ((double)a0[c].z * wk0.z + (double)a0[c].w * wk0.w)
             + ((double)a1[c].x * wk1.x + (double)a1[c].y * wk1.y)
             + ((double)a1[c].z * wk1.z + (double)a1[c].w * wk1.w);
    }
  }

  const double qdt = qd + (double)bq[h * DK_ + lane];
  const double bkd = (double)bk[h * DK_ + lane];
  double scf[12];
  #pragma unroll
  for (int c = 0; c < 12; c++){
    double p = qdt * (sc[c] + bkd);
    p += __shfl_xor(p, 1);  p += __shfl_xor(p, 2);  p += __shfl_xor(p, 4);
    p += __shfl_xor(p, 8);  p += __shfl_xor(p, 16); p += __shfl_xor(p, 32);
    scf[c] = (ci[c] < 0 || ci[c] > q) ? -1e30 : p * 0.125;
  }

  // stable top-8 pick in fp64 (ties -> lowest key index)
  double t8v[8]; int t8i[8];
  #pragma unroll
  for (int r = 0; r < 8; r++){
    double m = scf[0];
    #pragma unroll
    for (int j = 1; j < 12; j++) m = fmax(m, scf[j]);
    int jidx = 0x7fffffff;
    #pragma unroll
    for (int j = 0; j < 12; j++) if (scf[j] == m) jidx = min(jidx, ci[j]);
    #pragma unroll
    for (int j = 0; j < 12; j++) if (scf[j] == m && ci[j] == jidx) scf[j] = -3e30;
    t8v[r] = m; t8i[r] = jidx;
  }

  float w8[8]; float Z = 0.f;
  #pragma unroll
  for (int j = 0; j < 8; j++){
    w8[j] = __expf((float)(t8v[j] - t8v[0]));
    Z += w8[j];
  }
  float inv = 1.0f / Z;

  const float* vb = Vf + (size_t)(b * H_ + h) * S_ * DK_;
  float acc = 0.f;
  #pragma unroll
  for (int j = 0; j < 8; j++){
    int idx = t8i[j] < 0 ? 0 : t8i[j];
    acc += (w8[j] * inv) * vb[(size_t)idx * DK_ + lane];
  }
  ctxb[((size_t)b * S_ + q) * D_ + h * DK_ + lane] = f2bf(acc);
}

// ---------------- host ----------------
extern "C" void kernel_launch(void* const* d_in, const int* in_sizes, int n_in,
                              void* d_out, int out_size, void* d_ws, size_t ws_size,
                              hipStream_t stream)
{
  const float* x  = (const float*)d_in[0];
  const float* Wq = (const float*)d_in[1];
  const float* bq = (const float*)d_in[2];
  const float* Wk = (const float*)d_in[3];
  const float* bk = (const float*)d_in[4];
  const float* Wv = (const float*)d_in[5];
  const float* bv = (const float*)d_in[6];
  const float* Wo = (const float*)d_in[7];
  const float* bo = (const float*)d_in[8];
  const float* g1 = (const float*)d_in[9];
  const float* W1 = (const float*)d_in[10];
  const float* b1 = (const float*)d_in[11];
  const float* W2 = (const float*)d_in[12];
  const float* b2 = (const float*)d_in[13];
  const float* g2 = (const float*)d_in[14];
  float* out = (float*)d_out;
  char* ws = (char*)d_ws;

  size_t o = 0;
  auto take = [&](size_t bytes){ size_t r = o; o += (bytes + 255) & ~(size_t)255; return r; };
  unsigned short* xh   = (unsigned short*)(ws + take(8388608));
  unsigned short* xl   = (unsigned short*)(ws + take(8388608));
  unsigned short* QKh  = (unsigned short*)(ws + take(16777216));
  unsigned short* QKl  = (unsigned short*)(ws + take(16777216));
  unsigned short* Wqkh = (unsigned short*)(ws + take(4194304));
  unsigned short* Wqkl = (unsigned short*)(ws + take(4194304));
  unsigned short* Wvb  = (unsigned short*)(ws + take(2097152));
  unsigned short* Wob  = (unsigned short*)(ws + take(2097152));
  unsigned short* W1b  = (unsigned short*)(ws + take(8388608));
  unsigned short* W2b  = (unsigned short*)(ws + take(8388608));
  float*          Vf   = (float*)(ws + take(16777216));
  unsigned short* ctxb = (unsigned short*)(ws + take(8388608));
  unsigned short* ub   = (unsigned short*)(ws + take(8388608));
  int*            cand = (int*)(ws + take((size_t)NROWS * 12 * 4));
  unsigned int*   flg  = (unsigned int*)(ws + take((size_t)NROWS * 4));
  // t (4096x4096 bf16, 32MB) aliases [xh, xl, QKh] which are all dead before MLP1
  unsigned short* tb   = (unsigned short*)ws;

  convert_all<<<2048, 256, 0, stream>>>(x, Wq, Wk, Wv, Wo, W1, W2,
                                        xh, xl, Wqkh, Wqkl, Wvb, Wob, W1b, W2b);
  gemm_bt<4, EPI_QK><<<dim3(16, 32), 256, 0, stream>>>(
      xh, xl, Wqkh, Wqkl, 4096, 2048, 1024, bq, bk, nullptr, QKh, QKl);
  gemm_bt<1, EPI_V><<<dim3(8, 32), 256, 0, stream>>>(
      xh, nullptr, Wvb, nullptr, 4096, 1024, 1024, bv, nullptr, nullptr, Vf, nullptr);
  attn_topk<<<dim3(16, 16, 2), 256, 0, stream>>>(QKh, QKl, Vf, ctxb, cand, flg);
  rescue<<<dim3(NROWS / 4), 256, 0, stream>>>(x, Wq, bq, Wk, bk, Vf, cand, flg, ctxb);
  gemm_bt<1, EPI_WO><<<dim3(8, 32), 256, 0, stream>>>(
      ctxb, nullptr, Wob, nullptr, 4096, 1024, 1024, bo, nullptr, g1, ub, nullptr);
  gemm_bt<1, EPI_GELU><<<dim3(32, 32), 256, 0, stream>>>(
      ub, nullptr, W1b, nullptr, 4096, 4096, 1024, b1, nullptr, nullptr, tb, nullptr);
  gemm_bt<1, EPI_OUT><<<dim3(8, 32), 256, 0, stream>>>(
      tb, nullptr, W2b, nullptr, 4096, 1024, 4096, b2, nullptr, g2, out, nullptr);
}

// Round 7
// 908.096 us; speedup vs baseline: 1.3796x; 1.3796x over previous
//
#include <hip/hip_runtime.h>
#include <hip/hip_bf16.h>
#include <cstdint>

#define B_ 2
#define S_ 2048
#define D_ 1024
#define H_ 16
#define DK_ 64
#define QK_ELEMS ((size_t)4194304)   // B*H*S*DK
#define NROWS 65536                  // B*H*S
#define TAU 8e-5f

typedef __attribute__((ext_vector_type(8))) short bf16x8;
typedef __attribute__((ext_vector_type(4))) float f32x4;
typedef __attribute__((ext_vector_type(16))) float f32x16;
typedef __attribute__((ext_vector_type(4))) unsigned short us4;

__device__ __forceinline__ unsigned short f2bf(float f){
  unsigned int u = __float_as_uint(f);
  unsigned int r = u + 0x7fffu + ((u >> 16) & 1u);
  return (unsigned short)(r >> 16);
}
__device__ __forceinline__ float bf2f(unsigned short h){
  return __uint_as_float(((unsigned int)h) << 16);
}

__device__ __forceinline__ void gload16(const void* g, void* l){
  __builtin_amdgcn_global_load_lds(
    (__attribute__((address_space(1))) void*)(void*)(g),
    (__attribute__((address_space(3))) void*)(l), 16, 0, 0);
}

__device__ __forceinline__ f32x4 mfma16(bf16x8 a, bf16x8 b, f32x4 c){
  return __builtin_amdgcn_mfma_f32_16x16x32_bf16(a, b, c, 0, 0, 0);
}
__device__ __forceinline__ f32x16 mfma32(bf16x8 a, bf16x8 b, f32x16 c){
  return __builtin_amdgcn_mfma_f32_32x32x16_bf16(a, b, c, 0, 0, 0);
}

// ---------------- conversion: fp32 -> bf16 (hi/lo splits where needed) ----------------
__global__ __launch_bounds__(256) void convert_all(
  const float* __restrict__ x,  const float* __restrict__ Wq, const float* __restrict__ Wk,
  const float* __restrict__ Wv, const float* __restrict__ Wo, const float* __restrict__ W1,
  const float* __restrict__ W2,
  unsigned short* __restrict__ xh, unsigned short* __restrict__ xl,
  unsigned short* __restrict__ Wqkh, unsigned short* __restrict__ Wqkl,
  unsigned short* __restrict__ Wvb, unsigned short* __restrict__ Wob,
  unsigned short* __restrict__ W1b, unsigned short* __restrict__ W2b)
{
  const long total = 16777216 / 4;
  for (long i = (long)blockIdx.x * blockDim.x + threadIdx.x; i < total;
       i += (long)gridDim.x * blockDim.x) {
    long e = i * 4;
    const float* src; unsigned short* dh; unsigned short* dl = nullptr; long o;
    if      (e < 4194304)  { src = x;  dh = xh;            dl = xl;            o = e; }
    else if (e < 5242880)  { src = Wq; dh = Wqkh;          dl = Wqkl;          o = e - 4194304; }
    else if (e < 6291456)  { src = Wk; dh = Wqkh + 1048576; dl = Wqkl + 1048576; o = e - 5242880; }
    else if (e < 7340032)  { src = Wv; dh = Wvb;           o = e - 6291456; }
    else if (e < 8388608)  { src = Wo; dh = Wob;           o = e - 7340032; }
    else if (e < 12582912) { src = W1; dh = W1b;           o = e - 8388608; }
    else                   { src = W2; dh = W2b;           o = e - 12582912; }
    float4 v = *(const float4*)(src + o);
    us4 h;
    h.x = f2bf(v.x); h.y = f2bf(v.y); h.z = f2bf(v.z); h.w = f2bf(v.w);
    *(us4*)(dh + o) = h;
    if (dl) {
      us4 L;
      L.x = f2bf(v.x - bf2f(h.x));
      L.y = f2bf(v.y - bf2f(h.y));
      L.z = f2bf(v.z - bf2f(h.z));
      L.w = f2bf(v.w - bf2f(h.w));
      *(us4*)(dl + o) = L;
    }
  }
}

// ---------------- generic B^T GEMM: C[m][n] = sum_k A[m][k]*B[n][k] ----------------
#define EPI_QK   0
#define EPI_V    1
#define EPI_WO   2
#define EPI_GELU 3
#define EPI_OUT  4

template<int NT, int EPI>
__global__ __launch_bounds__(256) void gemm_bt(
  const unsigned short* __restrict__ A,  const unsigned short* __restrict__ Alo,
  const unsigned short* __restrict__ Bm, const unsigned short* __restrict__ Blo,
  int M, int N, int K,
  const float* __restrict__ bias0, const float* __restrict__ bias1,
  const float* __restrict__ gsc,
  void* __restrict__ out0, void* __restrict__ out1)
{
  constexpr int NTILES = (NT > 1) ? 4 : 2;
  __shared__ char lds[NTILES * 8192];
  char* Ahl = lds;
  char* Bhl = lds + 8192;
  char* All = lds + 16384;
  char* Bll = lds + 24576;
  const int tid = threadIdx.x;
  const int wid = tid >> 6, lane = tid & 63;
  const int mtile = blockIdx.y, ntile = blockIdx.x;
  const int wm = wid >> 1, wn = wid & 1;

  f32x4 acc[4][4];
  #pragma unroll
  for (int i = 0; i < 4; i++)
    #pragma unroll
    for (int j = 0; j < 4; j++)
      #pragma unroll
      for (int r = 0; r < 4; r++) acc[i][j][r] = 0.f;

  const unsigned short* Abase  = A  + (size_t)(mtile * 128) * K;
  const unsigned short* Bbase  = Bm + (size_t)(ntile * 128) * K;
  const unsigned short* Albase = (NT > 1) ? Alo + (size_t)(mtile * 128) * K : nullptr;
  const unsigned short* Blbase = (NT > 1) ? Blo + (size_t)(ntile * 128) * K : nullptr;

  auto stage = [&](char* ldst, const unsigned short* gsrc, int kb){
    #pragma unroll
    for (int j = 0; j < 2; j++){
      int seg = wid + 4 * j;                 // 0..7, 1KB each
      int row = seg * 16 + (lane >> 2);      // 0..127
      int c   = (lane & 3) ^ ((row >> 1) & 3);
      gload16(gsrc + (size_t)row * K + kb + c * 8, ldst + seg * 1024);
    }
  };

  for (int kb = 0; kb < K; kb += 32){
    stage(Ahl, Abase, kb);
    stage(Bhl, Bbase, kb);
    if (NT > 1){ stage(All, Albase, kb); stage(Bll, Blbase, kb); }
    __syncthreads();

    bf16x8 af[4], bfr[4], afl[4], bfl[4];
    #pragma unroll
    for (int i = 0; i < 4; i++){
      int ra = wm * 64 + i * 16 + (lane & 15);
      int oa = ra * 64 + (((lane >> 4) ^ ((ra >> 1) & 3)) * 16);
      af[i] = *(const bf16x8*)(Ahl + oa);
      if (NT > 1) afl[i] = *(const bf16x8*)(All + oa);
      int rb = wn * 64 + i * 16 + (lane & 15);
      int ob = rb * 64 + (((lane >> 4) ^ ((rb >> 1) & 3)) * 16);
      bfr[i] = *(const bf16x8*)(Bhl + ob);
      if (NT > 1) bfl[i] = *(const bf16x8*)(Bll + ob);
    }
    #pragma unroll
    for (int i = 0; i < 4; i++)
      #pragma unroll
      for (int j = 0; j < 4; j++){
        if (NT > 1){
          acc[i][j] = mfma16(afl[i], bfl[j], acc[i][j]);
          acc[i][j] = mfma16(afl[i], bfr[j], acc[i][j]);
          acc[i][j] = mfma16(af[i],  bfl[j], acc[i][j]);
        }
        acc[i][j] = mfma16(af[i], bfr[j], acc[i][j]);
      }
    __syncthreads();
  }

  float g2x = 1.0f;
  if (EPI == EPI_WO || EPI == EPI_OUT) g2x = 2.0f * gsc[0];

  #pragma unroll
  for (int j = 0; j < 4; j++){
    int n = ntile * 128 + wn * 64 + j * 16 + (lane & 15);
    float bn;
    if (EPI == EPI_QK) bn = (n < 1024) ? bias0[n] : bias1[n - 1024];
    else               bn = bias0[n];
    #pragma unroll
    for (int i = 0; i < 4; i++){
      int mb = mtile * 128 + wm * 64 + i * 16 + ((lane >> 4) << 2);
      #pragma unroll
      for (int r = 0; r < 4; r++){
        int m = mb + r;
        float val = acc[i][j][r] + bn;
        if (EPI == EPI_QK){
          if (n < 1024) val *= 0.125f;          // fold 1/sqrt(DK) into q
          int dd = n & 63, hh = (n >> 6) & 15, isK = n >> 10;
          size_t off = ((size_t)((m >> 11) * H_ + hh) * S_ + (m & 2047)) * DK_ + dd
                       + (size_t)isK * QK_ELEMS;
          unsigned short hi = f2bf(val);
          ((unsigned short*)out0)[off] = hi;
          ((unsigned short*)out1)[off] = f2bf(val - bf2f(hi));
        } else if (EPI == EPI_V){
          int dd = n & 63, hh = n >> 6;
          size_t off = ((size_t)((m >> 11) * H_ + hh) * S_ + (m & 2047)) * DK_ + dd;
          ((float*)out0)[off] = val;
        } else if (EPI == EPI_WO){
          ((unsigned short*)out0)[(size_t)m * 1024 + n] = f2bf(val * g2x);
        } else if (EPI == EPI_GELU){
          float t = 0.5f * val * (1.0f + erff(val * 0.70710678118654752f));
          ((unsigned short*)out0)[(size_t)m * 4096 + n] = f2bf(t);
        } else {
          ((float*)out0)[(size_t)m * 1024 + n] = val * g2x;
        }
      }
    }
  }
}

// ---------------- attention: causal scores + top-12 tracking + softmax + PV ----------------
template<int NK>
__device__ __forceinline__ void topk_insert(float (&tv)[NK], int (&ti)[NK],
                                            float& minv, int& minslot, float s, int kidx){
  #pragma unroll
  for (int j = 0; j < NK; j++){
    bool sel = (j == minslot);
    tv[j] = sel ? s    : tv[j];
    ti[j] = sel ? kidx : ti[j];
  }
  minv = tv[0]; minslot = 0;
  #pragma unroll
  for (int j = 1; j < NK; j++){
    bool lt = tv[j] < minv;
    minv    = lt ? tv[j] : minv;
    minslot = lt ? j     : minslot;
  }
}

__global__ __launch_bounds__(256) void attn_topk(
  const unsigned short* __restrict__ QKh, const unsigned short* __restrict__ QKl,
  const float* __restrict__ Vf, unsigned short* __restrict__ ctxb,
  int* __restrict__ cand, unsigned int* __restrict__ flags)
{
  __shared__ char lds[16384];   // Khi 8KB + Klo 8KB (64 keys x 64 dk bf16, swizzled)
  const int tid = threadIdx.x, wid = tid >> 6, lane = tid & 63;
  const int b = blockIdx.z, h = blockIdx.y, qt = blockIdx.x;
  const int bh = b * H_ + h;
  const size_t base = (size_t)bh * S_ * DK_;
  const unsigned short* qh = QKh + base;
  const unsigned short* ql = QKl + base;
  const unsigned short* kh = QKh + QK_ELEMS + base;
  const unsigned short* kl = QKl + QK_ELEMS + base;
  const int Q0  = qt * 128;
  const int q0w = Q0 + wid * 32;
  const int qg  = q0w + (lane & 31);

  bf16x8 qfh[4], qfl[4];
  #pragma unroll
  for (int kk = 0; kk < 4; kk++){
    size_t o = (size_t)(q0w + (lane & 31)) * DK_ + kk * 16 + (lane >> 5) * 8;
    qfh[kk] = *(const bf16x8*)(qh + o);
    qfl[kk] = *(const bf16x8*)(ql + o);
  }

  float tv[12]; int ti[12];
  #pragma unroll
  for (int j = 0; j < 12; j++){ tv[j] = -1e30f; ti[j] = -1; }
  float minv = -1e30f; int minslot = 0;

  const int nblocks = (Q0 + 128) >> 6;
  for (int blk = 0; blk < nblocks; ++blk){
    const int kb = blk * 64;
    #pragma unroll
    for (int j = 0; j < 4; j++){
      int segall = wid * 4 + j;          // 0..15
      int tI  = segall >> 3;             // 0: Khi, 1: Klo
      int seg = segall & 7;
      int row = seg * 8 + (lane >> 3);
      int c   = (lane & 7) ^ (row & 7);
      const unsigned short* src = (tI ? kl : kh) + (size_t)(kb + row) * DK_ + c * 8;
      gload16(src, lds + tI * 8192 + seg * 1024);
    }
    __syncthreads();

    if (kb <= q0w + 31){
      #pragma unroll
      for (int sub = 0; sub < 2; ++sub){
        f32x16 acc;
        #pragma unroll
        for (int r = 0; r < 16; r++) acc[r] = 0.f;
        const int key_l = sub * 32 + (lane & 31);
        #pragma unroll
        for (int kk = 0; kk < 4; kk++){
          int cl  = kk * 2 + (lane >> 5);
          int off = key_l * 128 + ((cl ^ (key_l & 7)) * 16);
          bf16x8 ah = *(const bf16x8*)(lds + off);
          bf16x8 al = *(const bf16x8*)(lds + 8192 + off);
          acc = mfma32(al, qfl[kk], acc);
          acc = mfma32(al, qfh[kk], acc);
          acc = mfma32(ah, qfl[kk], acc);
          acc = mfma32(ah, qfh[kk], acc);
        }
        const int krow0 = kb + sub * 32 + ((lane >> 5) << 2);
        #pragma unroll
        for (int r = 0; r < 16; r++){
          float s = acc[r];
          int kidx = krow0 + (r & 3) + ((r >> 2) << 3);
          if ((kidx <= qg) && (s > minv))
            topk_insert(tv, ti, minv, minslot, s, kidx);
        }
      }
    }
    __syncthreads();
  }

  // merge the two key-halves (lane and lane^32 hold same q-row)
  {
    float sv[12]; int si[12];
    #pragma unroll
    for (int j = 0; j < 12; j++){ sv[j] = tv[j]; si[j] = ti[j]; }
    #pragma unroll
    for (int j = 0; j < 12; j++){
      float ov = __shfl_xor(sv[j], 32);
      int   oi = __shfl_xor(si[j], 32);
      if (ov > minv) topk_insert(tv, ti, minv, minslot, ov, oi);
    }
  }

  // stable sorted top-9 pick (ties -> lowest key index first, like lax.top_k)
  float t8v[9]; int t8i[9];
  {
    float sv[12]; int si[12];
    #pragma unroll
    for (int j = 0; j < 12; j++){ sv[j] = tv[j]; si[j] = ti[j]; }
    #pragma unroll
    for (int r = 0; r < 9; r++){
      float m = sv[0];
      #pragma unroll
      for (int j = 1; j < 12; j++) m = fmaxf(m, sv[j]);
      int jidx = 0x7fffffff;
      #pragma unroll
      for (int j = 0; j < 12; j++) if (sv[j] == m) jidx = min(jidx, si[j]);
      #pragma unroll
      for (int j = 0; j < 12; j++) if (sv[j] == m && si[j] == jidx) sv[j] = -3e30f;
      t8v[r] = m; t8i[r] = jidx;
    }
  }

  // candidate dump + near-tie flag (rescue pass re-ranks flagged rows in fp64).
  // q<8 rows: <=8 valid keys, all kept regardless of ordering -> selection exact, skip.
  if (lane < 32){
    int row = bh * S_ + qg;
    #pragma unroll
    for (int c = 0; c < 12; c++) cand[row * 12 + c] = ti[c];
    flags[row] = (qg >= 8 && (t8v[7] - t8v[8] < TAU)) ? 1u : 0u;
  }

  // softmax over kept 8 (sentinels exp() to 0)
  float m = t8v[0];
  float w[8]; float Z = 0.f;
  #pragma unroll
  for (int j = 0; j < 8; j++){ w[j] = __expf(t8v[j] - m); Z += w[j]; }
  float inv = 1.0f / Z;

  float cacc[32];
  #pragma unroll
  for (int t = 0; t < 32; t++) cacc[t] = 0.f;
  const int half = lane >> 5;
  const float* vb = Vf + base + half * 32;
  #pragma unroll 2
  for (int j = 0; j < 8; j++){
    float p = w[j] * inv;
    int idx = t8i[j] < 0 ? 0 : t8i[j];
    const float4* vp = (const float4*)(vb + (size_t)idx * DK_);
    #pragma unroll
    for (int t = 0; t < 8; t++){
      float4 vv = vp[t];
      cacc[4*t+0] += p * vv.x; cacc[4*t+1] += p * vv.y;
      cacc[4*t+2] += p * vv.z; cacc[4*t+3] += p * vv.w;
    }
  }

  unsigned short* dst = ctxb + ((size_t)b * S_ + qg) * D_ + h * DK_ + half * 32;
  #pragma unroll
  for (int t = 0; t < 4; t++){
    union { unsigned short u[8]; uint4 v; } pk;
    #pragma unroll
    for (int e = 0; e < 8; e++) pk.u[e] = f2bf(cacc[8*t + e]);
    *(uint4*)(dst + 8*t) = pk.v;
  }
}

// ---------------- rescue: fp64-exact re-rank of near-tie rows ----------------
// Candidate-parallel: one block (4 waves) per row; wave w computes the q-dot
// plus candidates 3w..3w+2 (4 independent fp64 chains/lane, 12 named float4
// loads per chunk -> ~80 VGPR, no scratch). Scores meet in a 12-entry LDS
// array; wave 0 does stable fp64 top-8 + softmax + PV. Round-5 lesson: 13
// chains/wave forced scratch spills (WRITE_SIZE 1.9MB); split the work instead.
__global__ __launch_bounds__(256, 1) void rescue(
  const float* __restrict__ x, const float* __restrict__ Wq, const float* __restrict__ bq,
  const float* __restrict__ Wk, const float* __restrict__ bk,
  const float* __restrict__ Vf, const int* __restrict__ cand,
  const unsigned int* __restrict__ flags, unsigned short* __restrict__ ctxb)
{
  const int row = blockIdx.x;
  if (!flags[row]) return;
  __shared__ double scL[12];
  __shared__ int    ciL[12];
  const int tid = threadIdx.x, wid = tid >> 6, lane = tid & 63;
  const int b = row >> 15, h = (row >> 11) & 15, q = row & 2047;

  int ci0, ci1, ci2;
  {
    const int cb = row * 12 + wid * 3;
    ci0 = cand[cb + 0]; ci1 = cand[cb + 1]; ci2 = cand[cb + 2];
  }
  const float* xr  = x  + ((size_t)b * S_ + q) * D_;
  const float* wqr = Wq + (size_t)(h * DK_ + lane) * D_;
  const float* wkr = Wk + (size_t)(h * DK_ + lane) * D_;
  const float* xp0 = x + ((size_t)b * S_ + ((ci0 < 0 || ci0 > q) ? 0 : ci0)) * D_;
  const float* xp1 = x + ((size_t)b * S_ + ((ci1 < 0 || ci1 > q) ? 0 : ci1)) * D_;
  const float* xp2 = x + ((size_t)b * S_ + ((ci2 < 0 || ci2 > q) ? 0 : ci2)) * D_;

  double qd = 0.0, s0d = 0.0, s1d = 0.0, s2d = 0.0;
  for (int e = 0; e < D_; e += 8){
    float4 wq0 = *(const float4*)(wqr + e), wq1 = *(const float4*)(wqr + e + 4);
    float4 wk0 = *(const float4*)(wkr + e), wk1 = *(const float4*)(wkr + e + 4);
    float4 xq0 = *(const float4*)(xr  + e), xq1 = *(const float4*)(xr  + e + 4);
    float4 c0a = *(const float4*)(xp0 + e), c0b = *(const float4*)(xp0 + e + 4);
    float4 c1a = *(const float4*)(xp1 + e), c1b = *(const float4*)(xp1 + e + 4);
    float4 c2a = *(const float4*)(xp2 + e), c2b = *(const float4*)(xp2 + e + 4);
    qd  += ((double)xq0.x * wq0.x + (double)xq0.y * wq0.y)
         + ((double)xq0.z * wq0.z + (double)xq0.w * wq0.w)
         + ((double)xq1.x * wq1.x + (double)xq1.y * wq1.y)
         + ((double)xq1.z * wq1.z + (double)xq1.w * wq1.w);
    s0d += ((double)c0a.x * wk0.x + (double)c0a.y * wk0.y)
         + ((double)c0a.z * wk0.z + (double)c0a.w * wk0.w)
         + ((double)c0b.x * wk1.x + (double)c0b.y * wk1.y)
         + ((double)c0b.z * wk1.z + (double)c0b.w * wk1.w);
    s1d += ((double)c1a.x * wk0.x + (double)c1a.y * wk0.y)
         + ((double)c1a.z * wk0.z + (double)c1a.w * wk0.w)
         + ((double)c1b.x * wk1.x + (double)c1b.y * wk1.y)
         + ((double)c1b.z * wk1.z + (double)c1b.w * wk1.w);
    s2d += ((double)c2a.x * wk0.x + (double)c2a.y * wk0.y)
         + ((double)c2a.z * wk0.z + (double)c2a.w * wk0.w)
         + ((double)c2b.x * wk1.x + (double)c2b.y * wk1.y)
         + ((double)c2b.z * wk1.z + (double)c2b.w * wk1.w);
  }

  const double qdt = qd + (double)bq[h * DK_ + lane];
  const double bkd = (double)bk[h * DK_ + lane];
  {
    double p0 = qdt * (s0d + bkd);
    double p1 = qdt * (s1d + bkd);
    double p2 = qdt * (s2d + bkd);
    #pragma unroll
    for (int d = 1; d < 64; d <<= 1){
      p0 += __shfl_xor(p0, d);
      p1 += __shfl_xor(p1, d);
      p2 += __shfl_xor(p2, d);
    }
    if (lane == 0){
      scL[wid * 3 + 0] = (ci0 < 0 || ci0 > q) ? -1e30 : p0 * 0.125;
      scL[wid * 3 + 1] = (ci1 < 0 || ci1 > q) ? -1e30 : p1 * 0.125;
      scL[wid * 3 + 2] = (ci2 < 0 || ci2 > q) ? -1e30 : p2 * 0.125;
      ciL[wid * 3 + 0] = ci0;
      ciL[wid * 3 + 1] = ci1;
      ciL[wid * 3 + 2] = ci2;
    }
  }
  __syncthreads();

  if (wid == 0){
    double scf[12]; int cif[12];
    #pragma unroll
    for (int j = 0; j < 12; j++){ scf[j] = scL[j]; cif[j] = ciL[j]; }

    // stable top-8 pick in fp64 (ties -> lowest key index)
    double t8v[8]; int t8i[8];
    #pragma unroll
    for (int r = 0; r < 8; r++){
      double m = scf[0];
      #pragma unroll
      for (int j = 1; j < 12; j++) m = fmax(m, scf[j]);
      int jidx = 0x7fffffff;
      #pragma unroll
      for (int j = 0; j < 12; j++) if (scf[j] == m) jidx = min(jidx, cif[j]);
      #pragma unroll
      for (int j = 0; j < 12; j++) if (scf[j] == m && cif[j] == jidx) scf[j] = -3e30;
      t8v[r] = m; t8i[r] = jidx;
    }

    float w8[8]; float Z = 0.f;
    #pragma unroll
    for (int j = 0; j < 8; j++){
      w8[j] = __expf((float)(t8v[j] - t8v[0]));
      Z += w8[j];
    }
    float inv = 1.0f / Z;

    const float* vb = Vf + (size_t)(b * H_ + h) * S_ * DK_;
    float acc = 0.f;
    #pragma unroll
    for (int j = 0; j < 8; j++){
      int idx = t8i[j] < 0 ? 0 : t8i[j];
      acc += (w8[j] * inv) * vb[(size_t)idx * DK_ + lane];
    }
    ctxb[((size_t)b * S_ + q) * D_ + h * DK_ + lane] = f2bf(acc);
  }
}

// ---------------- host ----------------
extern "C" void kernel_launch(void* const* d_in, const int* in_sizes, int n_in,
                              void* d_out, int out_size, void* d_ws, size_t ws_size,
                              hipStream_t stream)
{
  const float* x  = (const float*)d_in[0];
  const float* Wq = (const float*)d_in[1];
  const float* bq = (const float*)d_in[2];
  const float* Wk = (const float*)d_in[3];
  const float* bk = (const float*)d_in[4];
  const float* Wv = (const float*)d_in[5];
  const float* bv = (const float*)d_in[6];
  const float* Wo = (const float*)d_in[7];
  const float* bo = (const float*)d_in[8];
  const float* g1 = (const float*)d_in[9];
  const float* W1 = (const float*)d_in[10];
  const float* b1 = (const float*)d_in[11];
  const float* W2 = (const float*)d_in[12];
  const float* b2 = (const float*)d_in[13];
  const float* g2 = (const float*)d_in[14];
  float* out = (float*)d_out;
  char* ws = (char*)d_ws;

  size_t o = 0;
  auto take = [&](size_t bytes){ size_t r = o; o += (bytes + 255) & ~(size_t)255; return r; };
  unsigned short* xh   = (unsigned short*)(ws + take(8388608));
  unsigned short* xl   = (unsigned short*)(ws + take(8388608));
  unsigned short* QKh  = (unsigned short*)(ws + take(16777216));
  unsigned short* QKl  = (unsigned short*)(ws + take(16777216));
  unsigned short* Wqkh = (unsigned short*)(ws + take(4194304));
  unsigned short* Wqkl = (unsigned short*)(ws + take(4194304));
  unsigned short* Wvb  = (unsigned short*)(ws + take(2097152));
  unsigned short* Wob  = (unsigned short*)(ws + take(2097152));
  unsigned short* W1b  = (unsigned short*)(ws + take(8388608));
  unsigned short* W2b  = (unsigned short*)(ws + take(8388608));
  float*          Vf   = (float*)(ws + take(16777216));
  unsigned short* ctxb = (unsigned short*)(ws + take(8388608));
  unsigned short* ub   = (unsigned short*)(ws + take(8388608));
  int*            cand = (int*)(ws + take((size_t)NROWS * 12 * 4));
  unsigned int*   flg  = (unsigned int*)(ws + take((size_t)NROWS * 4));
  // t (4096x4096 bf16, 32MB) aliases [xh, xl, QKh] which are all dead before MLP1
  unsigned short* tb   = (unsigned short*)ws;

  convert_all<<<2048, 256, 0, stream>>>(x, Wq, Wk, Wv, Wo, W1, W2,
                                        xh, xl, Wqkh, Wqkl, Wvb, Wob, W1b, W2b);
  gemm_bt<4, EPI_QK><<<dim3(16, 32), 256, 0, stream>>>(
      xh, xl, Wqkh, Wqkl, 4096, 2048, 1024, bq, bk, nullptr, QKh, QKl);
  gemm_bt<1, EPI_V><<<dim3(8, 32), 256, 0, stream>>>(
      xh, nullptr, Wvb, nullptr, 4096, 1024, 1024, bv, nullptr, nullptr, Vf, nullptr);
  attn_topk<<<dim3(16, 16, 2), 256, 0, stream>>>(QKh, QKl, Vf, ctxb, cand, flg);
  rescue<<<dim3(NROWS), 256, 0, stream>>>(x, Wq, bq, Wk, bk, Vf, cand, flg, ctxb);
  gemm_bt<1, EPI_WO><<<dim3(8, 32), 256, 0, stream>>>(
      ctxb, nullptr, Wob, nullptr, 4096, 1024, 1024, bo, nullptr, g1, ub, nullptr);
  gemm_bt<1, EPI_GELU><<<dim3(32, 32), 256, 0, stream>>>(
      ub, nullptr, W1b, nullptr, 4096, 4096, 1024, b1, nullptr, nullptr, tb, nullptr);
  gemm_bt<1, EPI_OUT><<<dim3(8, 32), 256, 0, stream>>>(
      tb, nullptr, W2b, nullptr, 4096, 1024, 4096, b2, nullptr, g2, out, nullptr);
}